// Round 2
// baseline (376.708 us; speedup 1.0000x reference)
//
#include <hip/hip_runtime.h>
#include <math.h>

#define S 128
#define H 64

// ---------------------------------------------------------------------------
// Exact-geometry occupancy mask (identical op sequence to the bit-exact round-0
// kernel; _rn intrinsics forbid fma contraction so floor() cells match numpy).
// ---------------------------------------------------------------------------
__device__ __forceinline__ bool sample_mask(
    float ox, float oy, float oz, float dx, float dy, float dz,
    float nr, float step, int s, const float* __restrict__ density)
{
    const float z  = __fadd_rn(nr, __fmul_rn((float)s, step));
    const float px = __fadd_rn(ox, __fmul_rn(z, dx));
    const float py = __fadd_rn(oy, __fmul_rn(z, dy));
    const float pz = __fadd_rn(oz, __fmul_rn(z, dz));
    const float gx = floorf(__fmul_rn(__fdiv_rn(__fsub_rn(px, -1.25f), 2.5f), 64.0f));
    const float gy = floorf(__fmul_rn(__fdiv_rn(__fsub_rn(py, -1.55f), 2.5f), 64.0f));
    const float gz = floorf(__fmul_rn(__fdiv_rn(__fsub_rn(pz, -1.25f), 2.5f), 64.0f));
    const int ix = (int)gx, iy = (int)gy, iz = (int)gz;
    const bool inb = (ix >= 0) && (ix < 64) && (iy >= 0) && (iy < 64) &&
                     (iz >= 0) && (iz < 64);
    const int cx = min(max(ix, 0), 63);
    const int cy = min(max(iy, 0), 63);
    const int cz = min(max(iz, 0), 63);
    const float dval = density[(cx << 12) | (cy << 6) | cz];
    return inb && (dval > 0.5f);
}

__global__ void zero_counter(int* c) { *c = 0; }

// ---------------------------------------------------------------------------
// K1: per-sample mask; compact active sample ids (ray<<7|s) into a global
// list. Inactive samples get alpha=0 (active ones are written by K2).
// ---------------------------------------------------------------------------
__global__ __launch_bounds__(256)
void mask_kernel(const float* __restrict__ rays_o, const float* __restrict__ rays_d,
                 const float* __restrict__ nearv, const float* __restrict__ farv,
                 const float* __restrict__ density,
                 unsigned int* __restrict__ list, int* __restrict__ counter,
                 float* __restrict__ alpha, int NS)
{
    const int gid = blockIdx.x * 256 + threadIdx.x;
    if (gid >= NS) return;
    const int ray = gid >> 7;
    const int s   = gid & (S - 1);
    const float ox = rays_o[ray * 3 + 0], oy = rays_o[ray * 3 + 1], oz = rays_o[ray * 3 + 2];
    const float dx = rays_d[ray * 3 + 0], dy = rays_d[ray * 3 + 1], dz = rays_d[ray * 3 + 2];
    const float nr = nearv[ray];
    const float step = __fdiv_rn(__fsub_rn(farv[ray], nr), 128.0f);
    const bool m = sample_mask(ox, oy, oz, dx, dy, dz, nr, step, s, density);
    if (m) {
        const int p = atomicAdd(counter, 1);   // compiler wave-coalesces this
        list[p] = (unsigned int)gid;
    } else {
        alpha[gid] = 0.0f;
    }
}

// ---------------------------------------------------------------------------
// K2: MLP over the compacted list. Persistent blocks (grid-stride), 256
// threads, 2 samples per thread so each wave-uniform ds_read_b128 of a W2 row
// feeds 8 FMAs -> VALU-bound inner loop.
// ---------------------------------------------------------------------------
__global__ __launch_bounds__(256)
void mlp_kernel(const unsigned int* __restrict__ list, const int* __restrict__ counter,
                const float* __restrict__ rays_o, const float* __restrict__ rays_d,
                const float* __restrict__ nearv, const float* __restrict__ farv,
                const float* __restrict__ jitter,
                const float* __restrict__ W1, const float* __restrict__ b1,
                const float* __restrict__ W2, const float* __restrict__ b2,
                const float* __restrict__ Wsig, const float* __restrict__ bsig,
                const float* __restrict__ Wrgb, const float* __restrict__ brgb,
                float* __restrict__ alpha, float* __restrict__ rgbout)
{
    __shared__ float sW2[H * H];     // 16 KB, [k][j]
    __shared__ float sW1[3 * H];
    __shared__ float sb1[H], sb2[H], sWsig[H];
    __shared__ float sWrgb[H * 3];
    __shared__ float sbias4[4];

    const int tid = threadIdx.x;
    const int total = *counter;
    if (blockIdx.x * 512 >= total) return;   // grid-stride is monotone

    for (int i = tid; i < H * H; i += 256) sW2[i] = W2[i];
    if (tid < 3 * H) { sW1[tid] = W1[tid]; sWrgb[tid] = Wrgb[tid]; }
    if (tid < H) { sb1[tid] = b1[tid]; sb2[tid] = b2[tid]; sWsig[tid] = Wsig[tid]; }
    if (tid == 0) {
        sbias4[0] = bsig[0];
        sbias4[1] = brgb[0]; sbias4[2] = brgb[1]; sbias4[3] = brgb[2];
    }
    __syncthreads();

    for (int base = blockIdx.x * 512; base < total; base += gridDim.x * 512) {
        const int ia = base + tid;
        const int ib = base + 256 + tid;
        const bool va = ia < total;
        const bool vb = ib < total;
        const unsigned int ga = va ? list[ia] : 0u;
        const unsigned int gb = vb ? list[ib] : 0u;

        float qax, qay, qaz, qbx, qby, qbz;
        {
            const int r = (int)(ga >> 7), s = (int)(ga & (S - 1));
            const float nr = nearv[r];
            const float step = __fdiv_rn(__fsub_rn(farv[r], nr), 128.0f);
            const float zs = __fadd_rn(nr, __fmul_rn((float)s, step));
            const float zj = zs + jitter[ga] * step;   // jitter[r*S+s] == jitter[ga]
            qax = rays_o[r * 3 + 0] + zj * rays_d[r * 3 + 0];
            qay = rays_o[r * 3 + 1] + zj * rays_d[r * 3 + 1];
            qaz = rays_o[r * 3 + 2] + zj * rays_d[r * 3 + 2];
        }
        {
            const int r = (int)(gb >> 7), s = (int)(gb & (S - 1));
            const float nr = nearv[r];
            const float step = __fdiv_rn(__fsub_rn(farv[r], nr), 128.0f);
            const float zs = __fadd_rn(nr, __fmul_rn((float)s, step));
            const float zj = zs + jitter[gb] * step;
            qbx = rays_o[r * 3 + 0] + zj * rays_d[r * 3 + 0];
            qby = rays_o[r * 3 + 1] + zj * rays_d[r * 3 + 1];
            qbz = rays_o[r * 3 + 2] + zj * rays_d[r * 3 + 2];
        }

        float h2a[H], h2b[H];
        #pragma unroll
        for (int j = 0; j < H; ++j) { h2a[j] = sb2[j]; h2b[j] = sb2[j]; }

        for (int k = 0; k < H; ++k) {
            const float h1a = fmaxf(
                fmaf(qax, sW1[k], fmaf(qay, sW1[H + k], fmaf(qaz, sW1[2 * H + k], sb1[k]))), 0.0f);
            const float h1b = fmaxf(
                fmaf(qbx, sW1[k], fmaf(qby, sW1[H + k], fmaf(qbz, sW1[2 * H + k], sb1[k]))), 0.0f);
            const float4* __restrict__ w2v = reinterpret_cast<const float4*>(&sW2[k * H]);
            #pragma unroll
            for (int j4 = 0; j4 < H / 4; ++j4) {
                const float4 w = w2v[j4];
                h2a[4 * j4 + 0] = fmaf(h1a, w.x, h2a[4 * j4 + 0]);
                h2a[4 * j4 + 1] = fmaf(h1a, w.y, h2a[4 * j4 + 1]);
                h2a[4 * j4 + 2] = fmaf(h1a, w.z, h2a[4 * j4 + 2]);
                h2a[4 * j4 + 3] = fmaf(h1a, w.w, h2a[4 * j4 + 3]);
                h2b[4 * j4 + 0] = fmaf(h1b, w.x, h2b[4 * j4 + 0]);
                h2b[4 * j4 + 1] = fmaf(h1b, w.y, h2b[4 * j4 + 1]);
                h2b[4 * j4 + 2] = fmaf(h1b, w.z, h2b[4 * j4 + 2]);
                h2b[4 * j4 + 3] = fmaf(h1b, w.w, h2b[4 * j4 + 3]);
            }
        }

        float siga = sbias4[0], car = sbias4[1], cag = sbias4[2], cab = sbias4[3];
        float sigb = sbias4[0], cbr = sbias4[1], cbg = sbias4[2], cbb = sbias4[3];
        #pragma unroll
        for (int j = 0; j < H; ++j) {
            const float va_ = fmaxf(h2a[j], 0.0f);
            const float vb_ = fmaxf(h2b[j], 0.0f);
            const float wr = sWrgb[j * 3 + 0], wg = sWrgb[j * 3 + 1], wb = sWrgb[j * 3 + 2];
            const float ws = sWsig[j];
            siga = fmaf(va_, ws, siga);
            car  = fmaf(va_, wr, car);
            cag  = fmaf(va_, wg, cag);
            cab  = fmaf(va_, wb, cab);
            sigb = fmaf(vb_, ws, sigb);
            cbr  = fmaf(vb_, wr, cbr);
            cbg  = fmaf(vb_, wg, cbg);
            cbb  = fmaf(vb_, wb, cbb);
        }

        if (va) {
            const int r = (int)(ga >> 7);
            const float step = __fdiv_rn(__fsub_rn(farv[r], nearv[r]), 128.0f);
            const float tau = fmaxf(siga, 0.0f) * step;
            alpha[ga] = 1.0f - expf(-tau);
            rgbout[ga * 3 + 0] = 1.0f / (1.0f + expf(-car));
            rgbout[ga * 3 + 1] = 1.0f / (1.0f + expf(-cag));
            rgbout[ga * 3 + 2] = 1.0f / (1.0f + expf(-cab));
        }
        if (vb) {
            const int r = (int)(gb >> 7);
            const float step = __fdiv_rn(__fsub_rn(farv[r], nearv[r]), 128.0f);
            const float tau = fmaxf(sigb, 0.0f) * step;
            alpha[gb] = 1.0f - expf(-tau);
            rgbout[gb * 3 + 0] = 1.0f / (1.0f + expf(-cbr));
            rgbout[gb * 3 + 1] = 1.0f / (1.0f + expf(-cbg));
            rgbout[gb * 3 + 2] = 1.0f / (1.0f + expf(-cbb));
        }
    }
}

// ---------------------------------------------------------------------------
// K3: wave-per-ray composite. 2 samples per lane (s=2l, 2l+1), shuffle-based
// product scan for transmittance, shuffle reduce for the color sum.
// Inactive samples have alpha==0 -> w==0 -> poison rgb contributes exactly +-0.
// ---------------------------------------------------------------------------
__global__ __launch_bounds__(256)
void composite_kernel(const float* __restrict__ alpha, const float* __restrict__ rgb,
                      float* __restrict__ out, int N)
{
    const int lane = threadIdx.x & 63;
    const int ray = blockIdx.x * 4 + (threadIdx.x >> 6);
    if (ray >= N) return;
    const int b0 = ray * S + 2 * lane;
    const float a0 = alpha[b0];
    const float a1 = alpha[b0 + 1];
    const float t0 = (1.0f - a0) + 1e-10f;
    const float t1 = (1.0f - a1) + 1e-10f;
    float v = t0 * t1;
    #pragma unroll
    for (int off = 1; off < 64; off <<= 1) {
        const float u = __shfl_up(v, off, 64);
        if (lane >= off) v *= u;
    }
    float excl = __shfl_up(v, 1, 64);
    if (lane == 0) excl = 1.0f;
    const float no_hit = __shfl(v, 63, 64);
    const float w0 = a0 * excl;
    const float w1 = a1 * (excl * t0);
    float cr = w0 * rgb[b0 * 3 + 0] + w1 * rgb[b0 * 3 + 3];
    float cg = w0 * rgb[b0 * 3 + 1] + w1 * rgb[b0 * 3 + 4];
    float cb = w0 * rgb[b0 * 3 + 2] + w1 * rgb[b0 * 3 + 5];
    #pragma unroll
    for (int off = 32; off >= 1; off >>= 1) {
        cr += __shfl_xor(cr, off, 64);
        cg += __shfl_xor(cg, off, 64);
        cb += __shfl_xor(cb, off, 64);
    }
    if (lane == 0) {
        out[ray * 3 + 0] = cr + no_hit;
        out[ray * 3 + 1] = cg + no_hit;
        out[ray * 3 + 2] = cb + no_hit;
    }
}

// ---------------------------------------------------------------------------
// Fallback: round-0 monolithic kernel (used only if ws_size is too small).
// ---------------------------------------------------------------------------
__global__ __launch_bounds__(128)
void raymarch_fallback(const float* __restrict__ rays_o, const float* __restrict__ rays_d,
                       const float* __restrict__ nearv, const float* __restrict__ farv,
                       const float* __restrict__ jitter, const float* __restrict__ density,
                       const float* __restrict__ W1, const float* __restrict__ b1,
                       const float* __restrict__ W2, const float* __restrict__ b2,
                       const float* __restrict__ Wsig, const float* __restrict__ bsig,
                       const float* __restrict__ Wrgb, const float* __restrict__ brgb,
                       float* __restrict__ out)
{
    __shared__ float sW2[H * H];
    __shared__ float sW1[3 * H];
    __shared__ float sb1[H], sb2[H], sWsig[H];
    __shared__ float sWrgb[H * 3];
    __shared__ float s_alpha[S], s_cr[S], s_cg[S], s_cb[S], s_scan[S];
    __shared__ int s_list[S];
    __shared__ int s_count;
    __shared__ float s_bias4[4];

    const int tid = threadIdx.x;
    const int ray = blockIdx.x;
    for (int i = tid; i < H * H; i += 128) sW2[i] = W2[i];
    for (int i = tid; i < 3 * H; i += 128) { sW1[i] = W1[i]; sWrgb[i] = Wrgb[i]; }
    if (tid < H) { sb1[tid] = b1[tid]; sb2[tid] = b2[tid]; sWsig[tid] = Wsig[tid]; }
    if (tid == 0) {
        s_count = 0;
        s_bias4[0] = bsig[0];
        s_bias4[1] = brgb[0]; s_bias4[2] = brgb[1]; s_bias4[3] = brgb[2];
    }
    s_alpha[tid] = 0.0f; s_cr[tid] = 0.0f; s_cg[tid] = 0.0f; s_cb[tid] = 0.0f;
    __syncthreads();

    const float ox = rays_o[ray * 3 + 0], oy = rays_o[ray * 3 + 1], oz = rays_o[ray * 3 + 2];
    const float dx = rays_d[ray * 3 + 0], dy = rays_d[ray * 3 + 1], dz = rays_d[ray * 3 + 2];
    const float nr = nearv[ray];
    const float step = __fdiv_rn(__fsub_rn(farv[ray], nr), 128.0f);
    if (sample_mask(ox, oy, oz, dx, dy, dz, nr, step, tid, density)) {
        const int p = atomicAdd(&s_count, 1);
        s_list[p] = tid;
    }
    __syncthreads();
    const int K = s_count;
    if (tid < K) {
        const int s = s_list[tid];
        const float zs = __fadd_rn(nr, __fmul_rn((float)s, step));
        const float zj = zs + jitter[ray * S + s] * step;
        const float qx = ox + zj * dx, qy = oy + zj * dy, qz = oz + zj * dz;
        float h2[H];
        #pragma unroll
        for (int j = 0; j < H; ++j) h2[j] = sb2[j];
        #pragma unroll 4
        for (int k = 0; k < H; ++k) {
            const float h1k = fmaxf(
                fmaf(qx, sW1[k], fmaf(qy, sW1[H + k], fmaf(qz, sW1[2 * H + k], sb1[k]))), 0.0f);
            const float* w2row = &sW2[k * H];
            #pragma unroll
            for (int j = 0; j < H; ++j) h2[j] = fmaf(h1k, w2row[j], h2[j]);
        }
        float sig = s_bias4[0], r = s_bias4[1], g = s_bias4[2], b = s_bias4[3];
        #pragma unroll
        for (int j = 0; j < H; ++j) {
            const float v = fmaxf(h2[j], 0.0f);
            sig = fmaf(v, sWsig[j], sig);
            r = fmaf(v, sWrgb[j * 3 + 0], r);
            g = fmaf(v, sWrgb[j * 3 + 1], g);
            b = fmaf(v, sWrgb[j * 3 + 2], b);
        }
        const float tau = fmaxf(sig, 0.0f) * step;
        s_alpha[s] = 1.0f - expf(-tau);
        s_cr[s] = 1.0f / (1.0f + expf(-r));
        s_cg[s] = 1.0f / (1.0f + expf(-g));
        s_cb[s] = 1.0f / (1.0f + expf(-b));
    }
    __syncthreads();
    const float term = (1.0f - s_alpha[tid]) + 1e-10f;
    s_scan[tid] = term;
    __syncthreads();
    #pragma unroll
    for (int off = 1; off < S; off <<= 1) {
        const float vs = s_scan[tid];
        const float vp = (tid >= off) ? s_scan[tid - off] : 1.0f;
        __syncthreads();
        s_scan[tid] = vs * vp;
        __syncthreads();
    }
    const float trans_ex = (tid == 0) ? 1.0f : s_scan[tid - 1];
    const float no_hit = s_scan[S - 1];
    const float w = s_alpha[tid] * trans_ex;
    const float cr = w * s_cr[tid], cg = w * s_cg[tid], cb = w * s_cb[tid];
    __syncthreads();
    s_cr[tid] = cr; s_cg[tid] = cg; s_cb[tid] = cb;
    __syncthreads();
    #pragma unroll
    for (int off = 64; off > 0; off >>= 1) {
        if (tid < off) {
            s_cr[tid] += s_cr[tid + off];
            s_cg[tid] += s_cg[tid + off];
            s_cb[tid] += s_cb[tid + off];
        }
        __syncthreads();
    }
    if (tid == 0) {
        out[ray * 3 + 0] = s_cr[0] + no_hit;
        out[ray * 3 + 1] = s_cg[0] + no_hit;
        out[ray * 3 + 2] = s_cb[0] + no_hit;
    }
}

extern "C" void kernel_launch(void* const* d_in, const int* in_sizes, int n_in,
                              void* d_out, int out_size, void* d_ws, size_t ws_size,
                              hipStream_t stream) {
    const float* rays_o  = (const float*)d_in[0];
    const float* rays_d  = (const float*)d_in[1];
    const float* nearv   = (const float*)d_in[2];
    const float* farv    = (const float*)d_in[3];
    const float* jitter  = (const float*)d_in[4];
    const float* density = (const float*)d_in[5];
    const float* W1      = (const float*)d_in[6];
    const float* b1      = (const float*)d_in[7];
    const float* W2      = (const float*)d_in[8];
    const float* b2      = (const float*)d_in[9];
    const float* Wsig    = (const float*)d_in[10];
    const float* bsig    = (const float*)d_in[11];
    const float* Wrgb    = (const float*)d_in[12];
    const float* brgb    = (const float*)d_in[13];
    float* out = (float*)d_out;

    const int N = in_sizes[2];
    const int NS = N * S;
    const size_t need = 256 + (size_t)NS * 4 + (size_t)NS * 4 + (size_t)NS * 12;

    if (ws_size < need) {
        raymarch_fallback<<<dim3(N), dim3(128), 0, stream>>>(
            rays_o, rays_d, nearv, farv, jitter, density,
            W1, b1, W2, b2, Wsig, bsig, Wrgb, brgb, out);
        return;
    }

    char* ws = (char*)d_ws;
    int* counter      = (int*)ws;
    unsigned int* lst = (unsigned int*)(ws + 256);
    float* alpha      = (float*)(ws + 256 + (size_t)NS * 4);
    float* rgbws      = (float*)(ws + 256 + (size_t)NS * 8);

    zero_counter<<<dim3(1), dim3(1), 0, stream>>>(counter);
    mask_kernel<<<dim3((NS + 255) / 256), dim3(256), 0, stream>>>(
        rays_o, rays_d, nearv, farv, density, lst, counter, alpha, NS);
    mlp_kernel<<<dim3(512), dim3(256), 0, stream>>>(
        lst, counter, rays_o, rays_d, nearv, farv, jitter,
        W1, b1, W2, b2, Wsig, bsig, Wrgb, brgb, alpha, rgbws);
    composite_kernel<<<dim3((N + 3) / 4), dim3(256), 0, stream>>>(alpha, rgbws, out, N);
}

// Round 3
// 152.253 us; speedup vs baseline: 2.4742x; 2.4742x over previous
//
#include <hip/hip_runtime.h>
#include <math.h>

#define S 128
#define H 64

// ---------------------------------------------------------------------------
// Exact-geometry occupancy mask (identical op sequence to the round-0 kernel;
// _rn intrinsics forbid fma contraction so floor() cells bit-match numpy).
// ---------------------------------------------------------------------------
__device__ __forceinline__ bool sample_mask(
    float ox, float oy, float oz, float dx, float dy, float dz,
    float nr, float step, int s, const float* __restrict__ density)
{
    const float z  = __fadd_rn(nr, __fmul_rn((float)s, step));
    const float px = __fadd_rn(ox, __fmul_rn(z, dx));
    const float py = __fadd_rn(oy, __fmul_rn(z, dy));
    const float pz = __fadd_rn(oz, __fmul_rn(z, dz));
    const float gx = floorf(__fmul_rn(__fdiv_rn(__fsub_rn(px, -1.25f), 2.5f), 64.0f));
    const float gy = floorf(__fmul_rn(__fdiv_rn(__fsub_rn(py, -1.55f), 2.5f), 64.0f));
    const float gz = floorf(__fmul_rn(__fdiv_rn(__fsub_rn(pz, -1.25f), 2.5f), 64.0f));
    const int ix = (int)gx, iy = (int)gy, iz = (int)gz;
    const bool inb = (ix >= 0) && (ix < 64) && (iy >= 0) && (iy < 64) &&
                     (iz >= 0) && (iz < 64);
    const int cx = min(max(ix, 0), 63);
    const int cy = min(max(iy, 0), 63);
    const int cz = min(max(iz, 0), 63);
    const float dval = density[(cx << 12) | (cy << 6) | cz];
    return inb && (dval > 0.5f);
}

__global__ void zero_counter(int* c) { *c = 0; }

// ---------------------------------------------------------------------------
// K1: mask + BLOCK-LEVEL compaction. 1024-thread blocks; wave ballot/popcount
// prefix + LDS scan of 16 wave counts; ONE atomicAdd per block (1024 atomics
// total vs round-2's 16384 wave-atomics that serialized to 149 us).
// ---------------------------------------------------------------------------
__global__ __launch_bounds__(1024)
void mask_kernel(const float* __restrict__ rays_o, const float* __restrict__ rays_d,
                 const float* __restrict__ nearv, const float* __restrict__ farv,
                 const float* __restrict__ density,
                 unsigned int* __restrict__ list, int* __restrict__ counter,
                 float* __restrict__ alpha, int NS)
{
    __shared__ int s_wcnt[16];
    __shared__ int s_wbase[16];
    __shared__ int s_gbase;

    const int tid  = threadIdx.x;
    const int lane = tid & 63;
    const int wv   = tid >> 6;
    const int gid  = blockIdx.x * 1024 + tid;

    bool m = false;
    if (gid < NS) {
        const int ray = gid >> 7;
        const int s   = gid & (S - 1);
        const float ox = rays_o[ray * 3 + 0], oy = rays_o[ray * 3 + 1], oz = rays_o[ray * 3 + 2];
        const float dx = rays_d[ray * 3 + 0], dy = rays_d[ray * 3 + 1], dz = rays_d[ray * 3 + 2];
        const float nr = nearv[ray];
        const float step = __fdiv_rn(__fsub_rn(farv[ray], nr), 128.0f);
        m = sample_mask(ox, oy, oz, dx, dy, dz, nr, step, s, density);
        if (!m) alpha[gid] = 0.0f;   // active ones are written by K2
    }

    const unsigned long long bal = __ballot(m);
    const int before = __popcll(bal & ((1ull << lane) - 1ull));
    if (lane == 0) s_wcnt[wv] = __popcll(bal);
    __syncthreads();
    if (tid == 0) {
        int tot = 0;
        #pragma unroll
        for (int i = 0; i < 16; ++i) { s_wbase[i] = tot; tot += s_wcnt[i]; }
        s_gbase = atomicAdd(counter, tot);
    }
    __syncthreads();
    if (m) list[s_gbase + s_wbase[wv] + before] = (unsigned int)gid;
}

// ---------------------------------------------------------------------------
// K2: MLP over the compacted list. ONE sample per thread (round-2's two
// samples hit the 256-VGPR cap -> 8.5% occupancy). All weight accesses use
// wave-uniform addresses straight from global: LLVM scalarizes them to
// s_load_* through the scalar cache (16 KB W2 fits), keeping the vector pipe
// purely on FMAs. h2[64] accumulator in VGPRs.
// ---------------------------------------------------------------------------
__global__ __launch_bounds__(256)
void mlp_kernel(const unsigned int* __restrict__ list, const int* __restrict__ counter,
                const float* __restrict__ rays_o, const float* __restrict__ rays_d,
                const float* __restrict__ nearv, const float* __restrict__ farv,
                const float* __restrict__ jitter,
                const float* __restrict__ W1, const float* __restrict__ b1,
                const float* __restrict__ W2, const float* __restrict__ b2,
                const float* __restrict__ Wsig, const float* __restrict__ bsig,
                const float* __restrict__ Wrgb, const float* __restrict__ brgb,
                float* __restrict__ alpha, float* __restrict__ rgbout)
{
    const int total = *counter;
    for (int i = blockIdx.x * 256 + threadIdx.x; i < total; i += gridDim.x * 256) {
        const unsigned int ga = list[i];
        const int r = (int)(ga >> 7);
        const int s = (int)(ga & (S - 1));
        const float nr = nearv[r];
        const float step = __fdiv_rn(__fsub_rn(farv[r], nr), 128.0f);
        const float zs = __fadd_rn(nr, __fmul_rn((float)s, step));
        const float zj = zs + jitter[ga] * step;
        const float qx = rays_o[r * 3 + 0] + zj * rays_d[r * 3 + 0];
        const float qy = rays_o[r * 3 + 1] + zj * rays_d[r * 3 + 1];
        const float qz = rays_o[r * 3 + 2] + zj * rays_d[r * 3 + 2];

        float h2[H];
        #pragma unroll
        for (int j = 0; j < H; ++j) h2[j] = b2[j];

        for (int k = 0; k < H; ++k) {
            const float h1k = fmaxf(
                fmaf(qx, W1[k], fmaf(qy, W1[H + k], fmaf(qz, W1[2 * H + k], b1[k]))), 0.0f);
            const float4* __restrict__ w2v = reinterpret_cast<const float4*>(W2 + (k << 6));
            #pragma unroll
            for (int j4 = 0; j4 < H / 4; ++j4) {
                const float4 w = w2v[j4];
                h2[4 * j4 + 0] = fmaf(h1k, w.x, h2[4 * j4 + 0]);
                h2[4 * j4 + 1] = fmaf(h1k, w.y, h2[4 * j4 + 1]);
                h2[4 * j4 + 2] = fmaf(h1k, w.z, h2[4 * j4 + 2]);
                h2[4 * j4 + 3] = fmaf(h1k, w.w, h2[4 * j4 + 3]);
            }
        }

        float sig = bsig[0], cr = brgb[0], cg = brgb[1], cb = brgb[2];
        #pragma unroll
        for (int j = 0; j < H; ++j) {
            const float v = fmaxf(h2[j], 0.0f);
            sig = fmaf(v, Wsig[j], sig);
            cr  = fmaf(v, Wrgb[j * 3 + 0], cr);
            cg  = fmaf(v, Wrgb[j * 3 + 1], cg);
            cb  = fmaf(v, Wrgb[j * 3 + 2], cb);
        }
        const float tau = fmaxf(sig, 0.0f) * step;
        alpha[ga] = 1.0f - expf(-tau);
        rgbout[ga * 3 + 0] = 1.0f / (1.0f + expf(-cr));
        rgbout[ga * 3 + 1] = 1.0f / (1.0f + expf(-cg));
        rgbout[ga * 3 + 2] = 1.0f / (1.0f + expf(-cb));
    }
}

// ---------------------------------------------------------------------------
// K3: wave-per-ray composite. 2 samples per lane, shuffle product scan for
// transmittance, shuffle reduce for color. Inactive samples have alpha==0 ->
// w==0 -> their (poisoned) rgb contributes exactly 0.
// ---------------------------------------------------------------------------
__global__ __launch_bounds__(256)
void composite_kernel(const float* __restrict__ alpha, const float* __restrict__ rgb,
                      float* __restrict__ out, int N)
{
    const int lane = threadIdx.x & 63;
    const int ray = blockIdx.x * 4 + (threadIdx.x >> 6);
    if (ray >= N) return;
    const int b0 = ray * S + 2 * lane;
    const float a0 = alpha[b0];
    const float a1 = alpha[b0 + 1];
    const float t0 = (1.0f - a0) + 1e-10f;
    const float t1 = (1.0f - a1) + 1e-10f;
    float v = t0 * t1;
    #pragma unroll
    for (int off = 1; off < 64; off <<= 1) {
        const float u = __shfl_up(v, off, 64);
        if (lane >= off) v *= u;
    }
    float excl = __shfl_up(v, 1, 64);
    if (lane == 0) excl = 1.0f;
    const float no_hit = __shfl(v, 63, 64);
    const float w0 = a0 * excl;
    const float w1 = a1 * (excl * t0);
    float cr = w0 * rgb[b0 * 3 + 0] + w1 * rgb[b0 * 3 + 3];
    float cg = w0 * rgb[b0 * 3 + 1] + w1 * rgb[b0 * 3 + 4];
    float cb = w0 * rgb[b0 * 3 + 2] + w1 * rgb[b0 * 3 + 5];
    #pragma unroll
    for (int off = 32; off >= 1; off >>= 1) {
        cr += __shfl_xor(cr, off, 64);
        cg += __shfl_xor(cg, off, 64);
        cb += __shfl_xor(cb, off, 64);
    }
    if (lane == 0) {
        out[ray * 3 + 0] = cr + no_hit;
        out[ray * 3 + 1] = cg + no_hit;
        out[ray * 3 + 2] = cb + no_hit;
    }
}

// ---------------------------------------------------------------------------
// Fallback: round-0 monolithic kernel (used only if ws_size is too small).
// ---------------------------------------------------------------------------
__global__ __launch_bounds__(128)
void raymarch_fallback(const float* __restrict__ rays_o, const float* __restrict__ rays_d,
                       const float* __restrict__ nearv, const float* __restrict__ farv,
                       const float* __restrict__ jitter, const float* __restrict__ density,
                       const float* __restrict__ W1, const float* __restrict__ b1,
                       const float* __restrict__ W2, const float* __restrict__ b2,
                       const float* __restrict__ Wsig, const float* __restrict__ bsig,
                       const float* __restrict__ Wrgb, const float* __restrict__ brgb,
                       float* __restrict__ out)
{
    __shared__ float sW2[H * H];
    __shared__ float sW1[3 * H];
    __shared__ float sb1[H], sb2[H], sWsig[H];
    __shared__ float sWrgb[H * 3];
    __shared__ float s_alpha[S], s_cr[S], s_cg[S], s_cb[S], s_scan[S];
    __shared__ int s_list[S];
    __shared__ int s_count;
    __shared__ float s_bias4[4];

    const int tid = threadIdx.x;
    const int ray = blockIdx.x;
    for (int i = tid; i < H * H; i += 128) sW2[i] = W2[i];
    for (int i = tid; i < 3 * H; i += 128) { sW1[i] = W1[i]; sWrgb[i] = Wrgb[i]; }
    if (tid < H) { sb1[tid] = b1[tid]; sb2[tid] = b2[tid]; sWsig[tid] = Wsig[tid]; }
    if (tid == 0) {
        s_count = 0;
        s_bias4[0] = bsig[0];
        s_bias4[1] = brgb[0]; s_bias4[2] = brgb[1]; s_bias4[3] = brgb[2];
    }
    s_alpha[tid] = 0.0f; s_cr[tid] = 0.0f; s_cg[tid] = 0.0f; s_cb[tid] = 0.0f;
    __syncthreads();

    const float ox = rays_o[ray * 3 + 0], oy = rays_o[ray * 3 + 1], oz = rays_o[ray * 3 + 2];
    const float dx = rays_d[ray * 3 + 0], dy = rays_d[ray * 3 + 1], dz = rays_d[ray * 3 + 2];
    const float nr = nearv[ray];
    const float step = __fdiv_rn(__fsub_rn(farv[ray], nr), 128.0f);
    if (sample_mask(ox, oy, oz, dx, dy, dz, nr, step, tid, density)) {
        const int p = atomicAdd(&s_count, 1);
        s_list[p] = tid;
    }
    __syncthreads();
    const int K = s_count;
    if (tid < K) {
        const int s = s_list[tid];
        const float zs = __fadd_rn(nr, __fmul_rn((float)s, step));
        const float zj = zs + jitter[ray * S + s] * step;
        const float qx = ox + zj * dx, qy = oy + zj * dy, qz = oz + zj * dz;
        float h2[H];
        #pragma unroll
        for (int j = 0; j < H; ++j) h2[j] = sb2[j];
        #pragma unroll 4
        for (int k = 0; k < H; ++k) {
            const float h1k = fmaxf(
                fmaf(qx, sW1[k], fmaf(qy, sW1[H + k], fmaf(qz, sW1[2 * H + k], sb1[k]))), 0.0f);
            const float* w2row = &sW2[k * H];
            #pragma unroll
            for (int j = 0; j < H; ++j) h2[j] = fmaf(h1k, w2row[j], h2[j]);
        }
        float sig = s_bias4[0], r = s_bias4[1], g = s_bias4[2], b = s_bias4[3];
        #pragma unroll
        for (int j = 0; j < H; ++j) {
            const float v = fmaxf(h2[j], 0.0f);
            sig = fmaf(v, sWsig[j], sig);
            r = fmaf(v, sWrgb[j * 3 + 0], r);
            g = fmaf(v, sWrgb[j * 3 + 1], g);
            b = fmaf(v, sWrgb[j * 3 + 2], b);
        }
        const float tau = fmaxf(sig, 0.0f) * step;
        s_alpha[s] = 1.0f - expf(-tau);
        s_cr[s] = 1.0f / (1.0f + expf(-r));
        s_cg[s] = 1.0f / (1.0f + expf(-g));
        s_cb[s] = 1.0f / (1.0f + expf(-b));
    }
    __syncthreads();
    const float term = (1.0f - s_alpha[tid]) + 1e-10f;
    s_scan[tid] = term;
    __syncthreads();
    #pragma unroll
    for (int off = 1; off < S; off <<= 1) {
        const float vs = s_scan[tid];
        const float vp = (tid >= off) ? s_scan[tid - off] : 1.0f;
        __syncthreads();
        s_scan[tid] = vs * vp;
        __syncthreads();
    }
    const float trans_ex = (tid == 0) ? 1.0f : s_scan[tid - 1];
    const float no_hit = s_scan[S - 1];
    const float w = s_alpha[tid] * trans_ex;
    const float cr = w * s_cr[tid], cg = w * s_cg[tid], cb = w * s_cb[tid];
    __syncthreads();
    s_cr[tid] = cr; s_cg[tid] = cg; s_cb[tid] = cb;
    __syncthreads();
    #pragma unroll
    for (int off = 64; off > 0; off >>= 1) {
        if (tid < off) {
            s_cr[tid] += s_cr[tid + off];
            s_cg[tid] += s_cg[tid + off];
            s_cb[tid] += s_cb[tid + off];
        }
        __syncthreads();
    }
    if (tid == 0) {
        out[ray * 3 + 0] = s_cr[0] + no_hit;
        out[ray * 3 + 1] = s_cg[0] + no_hit;
        out[ray * 3 + 2] = s_cb[0] + no_hit;
    }
}

extern "C" void kernel_launch(void* const* d_in, const int* in_sizes, int n_in,
                              void* d_out, int out_size, void* d_ws, size_t ws_size,
                              hipStream_t stream) {
    const float* rays_o  = (const float*)d_in[0];
    const float* rays_d  = (const float*)d_in[1];
    const float* nearv   = (const float*)d_in[2];
    const float* farv    = (const float*)d_in[3];
    const float* jitter  = (const float*)d_in[4];
    const float* density = (const float*)d_in[5];
    const float* W1      = (const float*)d_in[6];
    const float* b1      = (const float*)d_in[7];
    const float* W2      = (const float*)d_in[8];
    const float* b2      = (const float*)d_in[9];
    const float* Wsig    = (const float*)d_in[10];
    const float* bsig    = (const float*)d_in[11];
    const float* Wrgb    = (const float*)d_in[12];
    const float* brgb    = (const float*)d_in[13];
    float* out = (float*)d_out;

    const int N = in_sizes[2];
    const int NS = N * S;
    const size_t need = 256 + (size_t)NS * 4 + (size_t)NS * 4 + (size_t)NS * 12;

    if (ws_size < need) {
        raymarch_fallback<<<dim3(N), dim3(128), 0, stream>>>(
            rays_o, rays_d, nearv, farv, jitter, density,
            W1, b1, W2, b2, Wsig, bsig, Wrgb, brgb, out);
        return;
    }

    char* ws = (char*)d_ws;
    int* counter      = (int*)ws;
    unsigned int* lst = (unsigned int*)(ws + 256);
    float* alpha      = (float*)(ws + 256 + (size_t)NS * 4);
    float* rgbws      = (float*)(ws + 256 + (size_t)NS * 8);

    zero_counter<<<dim3(1), dim3(1), 0, stream>>>(counter);
    mask_kernel<<<dim3((NS + 1023) / 1024), dim3(1024), 0, stream>>>(
        rays_o, rays_d, nearv, farv, density, lst, counter, alpha, NS);
    mlp_kernel<<<dim3(1024), dim3(256), 0, stream>>>(
        lst, counter, rays_o, rays_d, nearv, farv, jitter,
        W1, b1, W2, b2, Wsig, bsig, Wrgb, brgb, alpha, rgbws);
    composite_kernel<<<dim3((N + 3) / 4), dim3(256), 0, stream>>>(alpha, rgbws, out, N);
}